// Round 8
// baseline (103.975 us; speedup 1.0000x reference)
//
#include <hip/hip_runtime.h>
#include <math.h>

#define N2   256
#define DIM  768
#define EPSF 1e-8f
#define MAGIC 0x5A17F00Du

// ws layout (float offsets). Every word is written before read on every call
// (flags rely on the per-call 0xAA poison != MAGIC). Total ~535 KB.
// NOTE (measured R4/R14): __threadfence()/grid.sync() = per-block L2 wb+inv
// -> 204us. Never wholesale-flush.
// NOTE (measured R15): all-blocks sc1 spin on few lines = LLC storm (45.7us).
// NOTE (measured R16): in-kernel barrier gating 896 consumers on 128
// producers loses to a kernel boundary (82.0 vs 77.7).
// NOTE (measured R17): removing the finalize node saved only 0.9us ->
// per-node overhead ~1us, NOT ~7us. R13 decomposition dead. Two candidate
// models now fit all data: (A) mega ~30-35us stall-bound; (B) mega ~8us +
// ~25us fixed non-kernel overhead per iteration.
// NOTE (R18, THIS ROUND = MEASUREMENT PROBE): launch mega 4x (idempotent:
// re-reads unchanged Gram, re-stores identical slot/flag values; block-0
// re-finalize writes identical out). dur delta vs R17 = 3*(mega+gap).
// Model A -> dur ~170-180; Model B -> dur ~100-105.
#define OFF_G     0u          // [2][65536] reduced Gram (s, t)   512 KB
#define OFF_DIAG  131072u     // [2][256]   diagonals
#define OFF_TSUM  131584u     // [2][64]    per-tile sums
#define OFF_SLOT  131712u     // [896] per-block result slots (sc1-only lines)
#define OFF_FLAG2 132608u     // [896] phaseB-done flags       (sc1-only lines)
#define SL_ANG  0     // [512]
#define SL_DIST 512   // [256]
#define SL_CON  768   // [128]

typedef __attribute__((ext_vector_type(8))) short short8;   // 8 bf16 = 4 VGPRs
typedef __attribute__((ext_vector_type(4))) float f32x4;

__device__ inline float wave_reduce_sum(float v) {
    #pragma unroll
    for (int o = 32; o > 0; o >>= 1) v += __shfl_down(v, o, 64);
    return v;
}
__device__ inline float wave_reduce_max(float v) {
    #pragma unroll
    for (int o = 32; o > 0; o >>= 1) v = fmaxf(v, __shfl_down(v, o, 64));
    return v;
}
__device__ inline float block_reduce_sum(float v, volatile float* red) {
    float w = wave_reduce_sum(v);
    __syncthreads();
    if ((threadIdx.x & 63) == 0) red[threadIdx.x >> 6] = w;
    __syncthreads();
    return red[0] + red[1] + red[2] + red[3];
}
__device__ inline const float* rowptr(const float* q, const float* p, int r) {
    return (r < 128) ? (r * DIM + q) : ((r - 128) * DIM + p);
}
__device__ inline unsigned f2bf(float x) {      // fp32 -> bf16 (RNE)
    union { float f; unsigned u; } v; v.f = x;
    return (v.u + 0x7fffu + ((v.u >> 16) & 1u)) >> 16;
}
// agent-scope (sc1) accessors: LLC-direct, no cache flushes.
__device__ inline void st_agent_f(float* p, float v) {
    __hip_atomic_store(p, v, __ATOMIC_RELAXED, __HIP_MEMORY_SCOPE_AGENT);
}
__device__ inline float ld_agent_f(const float* p) {
    return __hip_atomic_load(p, __ATOMIC_RELAXED, __HIP_MEMORY_SCOPE_AGENT);
}
__device__ inline void st_agent_u(unsigned* p, unsigned v) {
    __hip_atomic_store(p, v, __ATOMIC_RELAXED, __HIP_MEMORY_SCOPE_AGENT);
}
__device__ inline unsigned ld_agent_u(const unsigned* p) {
    return __hip_atomic_load(p, __ATOMIC_RELAXED, __HIP_MEMORY_SCOPE_AGENT);
}

// ---------------------------------------------------------------------------
// K1: full-K Gram GEMM via bf16 MFMA. 128 blocks x 256 threads. Normal
// stores; the following kernel boundary is the (free) coherence point.
// ---------------------------------------------------------------------------
__global__ __launch_bounds__(256) void gemm_kernel(
        const float* __restrict__ sq, const float* __restrict__ sp,
        const float* __restrict__ tq, const float* __restrict__ tp,
        float* __restrict__ ws) {
    const int b = blockIdx.x, t = threadIdx.x;
    const int mat = b & 1, tile = b >> 1;
    const int m0 = (tile >> 3) * 32, n0 = (tile & 7) * 32;
    const float* q = mat ? tq : sq;
    const float* p = mat ? tp : sp;

    __shared__ unsigned short Asb[32][104];   // bf16 [row][k], pad->208B rows
    __shared__ unsigned short Bsb[32][104];
    __shared__ float redg[4];

    // staging: 8 threads/row, each owns 12 floats (3 float4) per array
    const int srow = t >> 3, skq = (t & 7) * 12;
    const float* arow = rowptr(q, p, m0 + srow) + skq;
    const float* brow = rowptr(q, p, n0 + srow) + skq;

    float4 pa[3], pb[3];
    #pragma unroll
    for (int m = 0; m < 3; ++m) {
        pa[m] = *(const float4*)&arow[4 * m];
        pb[m] = *(const float4*)&brow[4 * m];
    }

    const int wave = t >> 6, lane = t & 63;
    const int wm = (wave >> 1) * 16, wn = (wave & 1) * 16;
    const int fr = lane & 15;          // fragment row/col
    const int fk = (lane >> 4) * 8;    // fragment k base
    f32x4 acc = {0.f, 0.f, 0.f, 0.f};

    for (int c = 0; c < 8; ++c) {
        // convert prefetched regs -> LDS
        #pragma unroll
        for (int m = 0; m < 3; ++m) {
            uint2 ap, bp;
            ap.x = f2bf(pa[m].x) | (f2bf(pa[m].y) << 16);
            ap.y = f2bf(pa[m].z) | (f2bf(pa[m].w) << 16);
            bp.x = f2bf(pb[m].x) | (f2bf(pb[m].y) << 16);
            bp.y = f2bf(pb[m].z) | (f2bf(pb[m].w) << 16);
            *(uint2*)&Asb[srow][skq + 4 * m] = ap;
            *(uint2*)&Bsb[srow][skq + 4 * m] = bp;
        }
        __syncthreads();
        if (c < 7) {      // prefetch next chunk
            const int kb = (c + 1) * 96;
            #pragma unroll
            for (int m = 0; m < 3; ++m) {
                pa[m] = *(const float4*)&arow[kb + 4 * m];
                pb[m] = *(const float4*)&brow[kb + 4 * m];
            }
        }
        #pragma unroll
        for (int kc = 0; kc < 96; kc += 32) {
            const short8 a0 = *(const short8*)&Asb[wm + fr][kc + fk];
            const short8 b0 = *(const short8*)&Bsb[wn + fr][kc + fk];
            acc = __builtin_amdgcn_mfma_f32_16x16x32_bf16(a0, b0, acc, 0, 0, 0);
        }
        __syncthreads();
    }

    // epilogue: C/D layout row=(lane>>4)*4+reg, col=lane&15
    float* G = ws + OFF_G + (unsigned)mat * 65536u;
    const int crow0 = (lane >> 4) * 4;
    const int ccol = lane & 15;
    float ts = 0.f;
    #pragma unroll
    for (int reg = 0; reg < 4; ++reg) {
        const int row = m0 + wm + crow0 + reg;
        const int col = n0 + wn + ccol;
        G[row * 256 + col] = acc[reg];
        ts += acc[reg];
    }
    if (m0 == n0 && wm == wn && (lane >> 4) == (ccol >> 2)) {
        // diagonal lanes: reg = ccol&3 hits row==col within diagonal quadrant
        ws[OFF_DIAG + (unsigned)(mat * 256 + m0 + wm + ccol)] = acc[ccol & 3];
    }
    const float tsum = block_reduce_sum(ts, redg);
    if (t == 0) ws[OFF_TSUM + (unsigned)(mat * 64 + tile)] = tsum;
}

// ---------------------------------------------------------------------------
// K2: mega kernel + inline finalize. 896 blocks x 256 threads.
// blocks 0..511 angle, 512..767 dist, 768..895 contrastive. Each block's t0:
// slot sc1 store -> vmcnt(0) -> flag sc1 store. Block 0 then polls the 896
// flags and finalizes into out. Idempotent by design (probe-safe).
// ---------------------------------------------------------------------------
__global__ __launch_bounds__(256, 4) void mega_kernel(float* __restrict__ ws,
                                                      float* __restrict__ out) {
    const float* Pg = ws + OFF_G;      // [2][65536]
    const float* Dg = ws + OFF_DIAG;   // [2][256]
    __shared__ float sGJ[16][68], sTJ[16][68], sIJ[16][68], sITJ[16][68];
    __shared__ float sGI[32][68], sTI[32][68];
    __shared__ float dgS[256], dgT[256];
    __shared__ float red1[4], red2[4], redS[1];
    const int b = blockIdx.x, t = threadIdx.x;

    if (b < 512) {
        // ---------------- angle ----------------
        const int k0 = (b & 3) * 64;
        const int j0 = ((b >> 2) & 15) * 16;
        const int i0 = (b >> 6) * 32;
        const int jj = t & 15, ii = t >> 4;
        const int i1 = i0 + ii, i2 = i1 + 16, j = j0 + jj;

        // diag (thread t owns index t)
        dgS[t] = Dg[t];
        dgT[t] = Dg[256 + t];

        // J-side G rows -> registers (1 float4 slot/thread)
        const int r = t >> 4, c4 = (t & 15) * 4;
        const unsigned baseJ = (unsigned)((j0 + r) * 256 + k0 + c4);
        const float4 gjs = *(const float4*)&Pg[baseJ];
        const float4 gjt = *(const float4*)&Pg[65536u + baseJ];

        // I-side G rows -> LDS (2 float4 slots/thread)
        #pragma unroll
        for (int s2 = 0; s2 < 2; ++s2) {
            const int slot = t + 256 * s2;
            const int ri = slot >> 4, ci = (slot & 15) * 4;
            const unsigned base = (unsigned)((i0 + ri) * 256 + k0 + ci);
            *(float4*)&sGI[ri][ci] = *(const float4*)&Pg[base];
            *(float4*)&sTI[ri][ci] = *(const float4*)&Pg[65536u + base];
        }
        // per-thread G[i1,j], G[i2,j] (both mats)
        const float g1s = Pg[(unsigned)(i1 * 256 + j)];
        const float g1t = Pg[65536u + (unsigned)(i1 * 256 + j)];
        const float g2s = Pg[(unsigned)(i2 * 256 + j)];
        const float g2t = Pg[65536u + (unsigned)(i2 * 256 + j)];
        __syncthreads();   // dgS/dgT ready

        // write J arrays + on-the-fly INV
        {
            const float djs = dgS[j0 + r], djt = dgT[j0 + r];
            float4 ivs, ivt;
            const float* dS = &dgS[k0 + c4];
            const float* dT = &dgT[k0 + c4];
            ivs.x = 1.f / (sqrtf(fmaxf(djs + dS[0] - 2.f * gjs.x, 0.f)) + EPSF);
            ivs.y = 1.f / (sqrtf(fmaxf(djs + dS[1] - 2.f * gjs.y, 0.f)) + EPSF);
            ivs.z = 1.f / (sqrtf(fmaxf(djs + dS[2] - 2.f * gjs.z, 0.f)) + EPSF);
            ivs.w = 1.f / (sqrtf(fmaxf(djs + dS[3] - 2.f * gjs.w, 0.f)) + EPSF);
            ivt.x = 1.f / (sqrtf(fmaxf(djt + dT[0] - 2.f * gjt.x, 0.f)) + EPSF);
            ivt.y = 1.f / (sqrtf(fmaxf(djt + dT[1] - 2.f * gjt.y, 0.f)) + EPSF);
            ivt.z = 1.f / (sqrtf(fmaxf(djt + dT[2] - 2.f * gjt.z, 0.f)) + EPSF);
            ivt.w = 1.f / (sqrtf(fmaxf(djt + dT[3] - 2.f * gjt.w, 0.f)) + EPSF);
            *(float4*)&sGJ[r][c4] = gjs;
            *(float4*)&sTJ[r][c4] = gjt;
            *(float4*)&sIJ[r][c4] = ivs;
            *(float4*)&sITJ[r][c4] = ivt;
        }
        // per-thread constants
        const float Gjj = dgS[j], Tjj = dgT[j];
        const float wis1 = 1.f / (sqrtf(fmaxf(dgS[i1] + Gjj - 2.f * g1s, 0.f)) + EPSF);
        const float wit1 = 1.f / (sqrtf(fmaxf(dgT[i1] + Tjj - 2.f * g1t, 0.f)) + EPSF);
        const float wis2 = 1.f / (sqrtf(fmaxf(dgS[i2] + Gjj - 2.f * g2s, 0.f)) + EPSF);
        const float wit2 = 1.f / (sqrtf(fmaxf(dgT[i2] + Tjj - 2.f * g2t, 0.f)) + EPSF);
        const float as1 = (Gjj - g1s) * wis1;
        const float at1 = (Tjj - g1t) * wit1;
        const float as2 = (Gjj - g2s) * wis2;
        const float at2 = (Tjj - g2t) * wit2;
        __syncthreads();   // all arrays ready

        float sum1 = 0.f, sum2 = 0.f;
        for (int c = 0; c < 64; c += 4) {
            const float4 gJ  = *(const float4*)&sGJ[jj][c];
            const float4 iJ  = *(const float4*)&sIJ[jj][c];
            const float4 tJ  = *(const float4*)&sTJ[jj][c];
            const float4 itJ = *(const float4*)&sITJ[jj][c];
            const float4 a1 = *(const float4*)&sGI[ii][c];
            const float4 b1 = *(const float4*)&sTI[ii][c];
            const float4 a2 = *(const float4*)&sGI[ii + 16][c];
            const float4 b2 = *(const float4*)&sTI[ii + 16][c];
            const float gJr[4]  = {gJ.x, gJ.y, gJ.z, gJ.w};
            const float iJr[4]  = {iJ.x, iJ.y, iJ.z, iJ.w};
            const float tJr[4]  = {tJ.x, tJ.y, tJ.z, tJ.w};
            const float itJr[4] = {itJ.x, itJ.y, itJ.z, itJ.w};
            const float a1r[4] = {a1.x, a1.y, a1.z, a1.w};
            const float b1r[4] = {b1.x, b1.y, b1.z, b1.w};
            const float a2r[4] = {a2.x, a2.y, a2.z, a2.w};
            const float b2r[4] = {b2.x, b2.y, b2.z, b2.w};
            #pragma unroll
            for (int e = 0; e < 4; ++e) {
                const float ps1 = fmaf(wis1, a1r[e] - gJr[e], as1) * iJr[e];
                const float pt1 = fmaf(wit1, b1r[e] - tJr[e], at1) * itJr[e];
                const float d1 = ps1 - pt1;
                const float ad1 = fabsf(d1);
                const float m1 = fminf(ad1, 1.f);
                sum1 = fmaf(m1, fmaf(-0.5f, m1, ad1), sum1);

                const float ps2 = fmaf(wis2, a2r[e] - gJr[e], as2) * iJr[e];
                const float pt2 = fmaf(wit2, b2r[e] - tJr[e], at2) * itJr[e];
                const float d2 = ps2 - pt2;
                const float ad2 = fabsf(d2);
                const float m2 = fminf(ad2, 1.f);
                sum2 = fmaf(m2, fmaf(-0.5f, m2, ad2), sum2);
            }
        }
        const float v = block_reduce_sum(sum1 + sum2, red1);
        if (t == 0) {
            st_agent_f(ws + OFF_SLOT + SL_ANG + b, v);
            asm volatile("s_waitcnt vmcnt(0)" ::: "memory");
            st_agent_u((unsigned*)(ws + OFF_FLAG2) + b, MAGIC);
        }
    } else if (b < 768) {
        // ---------------- distance row ----------------
        const int i = b - 512, j = t;
        const float gs  = Pg[(unsigned)(i * 256 + j)];
        const float gt  = Pg[65536u + (unsigned)(i * 256 + j)];
        const float djs = Dg[j], djt = Dg[256 + j];
        const float dis = Dg[i], dit = Dg[256 + i];
        const float ds = fmaxf(dis + djs - 2.f * gs, 0.f);
        const float dt = fmaxf(dit + djt - 2.f * gt, 0.f);

        // analytic masked pair-sums: sum_{i<j} d = N*tr - sum_all(G)
        const float tr_s = block_reduce_sum(djs, red1);
        const float tr_t = block_reduce_sum(djt, red1);
        const float tv = (t < 128) ? ws[OFF_TSUM + t] : 0.f;  // [2][64] linear
        const float sum_gs = block_reduce_sum((t < 64) ? tv : 0.f, red1);
        const float sum_gt = block_reduce_sum((t >= 64) ? tv : 0.f, red1);
        const float rs = 1.f / ((256.f * tr_s - sum_gs) / 32640.f + EPSF);
        const float rt = 1.f / ((256.f * tr_t - sum_gt) / 32640.f + EPSF);

        const float dd = ds * rs - dt * rt;
        const float a = fabsf(dd);
        const float m = fminf(a, 1.f);
        const float hv = block_reduce_sum((j > i) ? m * fmaf(-0.5f, m, a) : 0.f, red1);
        if (t == 0) {
            st_agent_f(ws + OFF_SLOT + SL_DIST + i, hv);
            asm volatile("s_waitcnt vmcnt(0)" ::: "memory");
            st_agent_u((unsigned*)(ws + OFF_FLAG2) + b, MAGIC);
        }
    } else {
        // ---------------- contrastive row ----------------
        const int rrow = b - 768, j = t;
        const float gs = (j >= 128) ? Pg[(unsigned)(rrow * 256 + j)] : 0.f;
        const float s = (j >= 128) ? 20.f * gs : -INFINITY;
        if (j == 128 + rrow) redS[0] = s;     // diag score
        float mx0 = wave_reduce_max(s);
        __syncthreads();
        if ((t & 63) == 0) red2[t >> 6] = mx0;
        __syncthreads();
        const float mx = fmaxf(fmaxf(red2[0], red2[1]), fmaxf(red2[2], red2[3]));
        const float e = block_reduce_sum((j >= 128) ? expf(s - mx) : 0.f, red1);
        if (t == 0) {
            st_agent_f(ws + OFF_SLOT + SL_CON + rrow, mx + logf(e) - redS[0]);
            asm volatile("s_waitcnt vmcnt(0)" ::: "memory");
            st_agent_u((unsigned*)(ws + OFF_FLAG2) + b, MAGIC);
        }
    }

    // ============== finalize (block 0 only) ==========
    if (b == 0) {
        for (int k = t; k < 896; k += 256) {   // one block polls: no storm
            while (ld_agent_u((const unsigned*)(ws + OFF_FLAG2) + k) != MAGIC)
                __builtin_amdgcn_s_sleep(4);
        }
        asm volatile("s_waitcnt vmcnt(0)" ::: "memory");
        __builtin_amdgcn_sched_barrier(0);
        __syncthreads();

        float* S = ws + OFF_SLOT;
        const float a_ = block_reduce_sum(ld_agent_f(S + SL_ANG + t) +
                                          ld_agent_f(S + SL_ANG + 256 + t), red1);
        const float d_ = block_reduce_sum(ld_agent_f(S + SL_DIST + t), red1);
        const float c_ = block_reduce_sum((t < 128) ? ld_agent_f(S + SL_CON + t)
                                                    : 0.f, red1);
        if (t == 0) {
            const float contrastive = c_ / 128.f;
            const float dist = d_ / 32640.f;
            const float ang = a_ / 16581120.f;   // 256*255*254
            const float kd = 0.5f * (dist + ang);
            out[0] = contrastive + kd;
            out[1] = contrastive;
            out[2] = kd;
        }
    }
}

extern "C" void kernel_launch(void* const* d_in, const int* in_sizes, int n_in,
                              void* d_out, int out_size, void* d_ws, size_t ws_size,
                              hipStream_t stream) {
    (void)in_sizes; (void)n_in; (void)out_size; (void)ws_size;
    const float* sq = (const float*)d_in[0];
    const float* sp = (const float*)d_in[1];
    const float* tq = (const float*)d_in[2];
    const float* tp = (const float*)d_in[3];
    float* ws  = (float*)d_ws;
    float* out = (float*)d_out;

    gemm_kernel<<<128, 256, 0, stream>>>(sq, sp, tq, tp, ws);
    // R18 probe: mega x4 (idempotent). dur delta vs R17 = 3*(mega + gap).
    mega_kernel<<<896, 256, 0, stream>>>(ws, out);
    mega_kernel<<<896, 256, 0, stream>>>(ws, out);
    mega_kernel<<<896, 256, 0, stream>>>(ws, out);
    mega_kernel<<<896, 256, 0, stream>>>(ws, out);
}

// Round 9
// 75.372 us; speedup vs baseline: 1.3795x; 1.3795x over previous
//
#include <hip/hip_runtime.h>
#include <math.h>

#define N2   256
#define DIM  768
#define EPSF 1e-8f
#define MAGIC 0x5A17F00Du

// ws layout (float offsets). Every word is written before read on every call
// (flags rely on the per-call 0xAA poison != MAGIC). Total ~535 KB.
// NOTE (measured R4/R14): __threadfence()/grid.sync() = per-block L2 wb+inv
// -> 204us. Never wholesale-flush.
// NOTE (measured R15): all-blocks sc1 spin on few lines = LLC storm (45.7us).
// NOTE (measured R16): in-kernel barrier gating consumers on producers loses
// to a kernel boundary (82.0 vs 77.7).
// NOTE (measured R17): removing a graph node saves only ~1us.
// NOTE (measured R18 probe, mega x4): mega+gap = 9.07us. Model B confirmed:
// dur = fill(~40.5) + fixed harness reset dispatches(~25) + gemm+gap(~2-4)
// + mega(~8). Controllable budget ~11us; structural floor ~65us.
// NOTE (R19, this round): angle i<->k symmetry. ps[i,j,k] symmetric in (i,k);
// masked terms self-cancel (huber(0)). Retile to 32x32 (i,k), launch 36
// unordered tile pairs x 16 j-tiles = 576 blocks; off-diag weight 2, diag 1.
// Terms 16.8M -> 9.4M, LDS reads 0.56x.
#define OFF_G     0u          // [2][65536] reduced Gram (s, t)   512 KB
#define OFF_DIAG  131072u     // [2][256]   diagonals
#define OFF_TSUM  131584u     // [2][64]    per-tile sums (+64 pad)
#define OFF_SLOT  131712u     // [960] per-block result slots (sc1-only lines)
#define OFF_FLAG2 132672u     // [960] done flags              (sc1-only lines)
#define SL_ANG  0     // [576]
#define SL_DIST 576   // [256]
#define SL_CON  832   // [128]
#define NB_ANG  576
#define NB_ALL  960

typedef __attribute__((ext_vector_type(8))) short short8;   // 8 bf16 = 4 VGPRs
typedef __attribute__((ext_vector_type(4))) float f32x4;

__device__ inline float wave_reduce_sum(float v) {
    #pragma unroll
    for (int o = 32; o > 0; o >>= 1) v += __shfl_down(v, o, 64);
    return v;
}
__device__ inline float wave_reduce_max(float v) {
    #pragma unroll
    for (int o = 32; o > 0; o >>= 1) v = fmaxf(v, __shfl_down(v, o, 64));
    return v;
}
__device__ inline float block_reduce_sum(float v, volatile float* red) {
    float w = wave_reduce_sum(v);
    __syncthreads();
    if ((threadIdx.x & 63) == 0) red[threadIdx.x >> 6] = w;
    __syncthreads();
    return red[0] + red[1] + red[2] + red[3];
}
__device__ inline const float* rowptr(const float* q, const float* p, int r) {
    return (r < 128) ? (r * DIM + q) : ((r - 128) * DIM + p);
}
__device__ inline unsigned f2bf(float x) {      // fp32 -> bf16 (RNE)
    union { float f; unsigned u; } v; v.f = x;
    return (v.u + 0x7fffu + ((v.u >> 16) & 1u)) >> 16;
}
// agent-scope (sc1) accessors: LLC-direct, no cache flushes.
__device__ inline void st_agent_f(float* p, float v) {
    __hip_atomic_store(p, v, __ATOMIC_RELAXED, __HIP_MEMORY_SCOPE_AGENT);
}
__device__ inline float ld_agent_f(const float* p) {
    return __hip_atomic_load(p, __ATOMIC_RELAXED, __HIP_MEMORY_SCOPE_AGENT);
}
__device__ inline void st_agent_u(unsigned* p, unsigned v) {
    __hip_atomic_store(p, v, __ATOMIC_RELAXED, __HIP_MEMORY_SCOPE_AGENT);
}
__device__ inline unsigned ld_agent_u(const unsigned* p) {
    return __hip_atomic_load(p, __ATOMIC_RELAXED, __HIP_MEMORY_SCOPE_AGENT);
}

// ---------------------------------------------------------------------------
// K1: full-K Gram GEMM via bf16 MFMA. 128 blocks x 256 threads. Normal
// stores; the following kernel boundary is the (free) coherence point.
// ---------------------------------------------------------------------------
__global__ __launch_bounds__(256) void gemm_kernel(
        const float* __restrict__ sq, const float* __restrict__ sp,
        const float* __restrict__ tq, const float* __restrict__ tp,
        float* __restrict__ ws) {
    const int b = blockIdx.x, t = threadIdx.x;
    const int mat = b & 1, tile = b >> 1;
    const int m0 = (tile >> 3) * 32, n0 = (tile & 7) * 32;
    const float* q = mat ? tq : sq;
    const float* p = mat ? tp : sp;

    __shared__ unsigned short Asb[32][104];   // bf16 [row][k], pad->208B rows
    __shared__ unsigned short Bsb[32][104];
    __shared__ float redg[4];

    // staging: 8 threads/row, each owns 12 floats (3 float4) per array
    const int srow = t >> 3, skq = (t & 7) * 12;
    const float* arow = rowptr(q, p, m0 + srow) + skq;
    const float* brow = rowptr(q, p, n0 + srow) + skq;

    float4 pa[3], pb[3];
    #pragma unroll
    for (int m = 0; m < 3; ++m) {
        pa[m] = *(const float4*)&arow[4 * m];
        pb[m] = *(const float4*)&brow[4 * m];
    }

    const int wave = t >> 6, lane = t & 63;
    const int wm = (wave >> 1) * 16, wn = (wave & 1) * 16;
    const int fr = lane & 15;          // fragment row/col
    const int fk = (lane >> 4) * 8;    // fragment k base
    f32x4 acc = {0.f, 0.f, 0.f, 0.f};

    for (int c = 0; c < 8; ++c) {
        // convert prefetched regs -> LDS
        #pragma unroll
        for (int m = 0; m < 3; ++m) {
            uint2 ap, bp;
            ap.x = f2bf(pa[m].x) | (f2bf(pa[m].y) << 16);
            ap.y = f2bf(pa[m].z) | (f2bf(pa[m].w) << 16);
            bp.x = f2bf(pb[m].x) | (f2bf(pb[m].y) << 16);
            bp.y = f2bf(pb[m].z) | (f2bf(pb[m].w) << 16);
            *(uint2*)&Asb[srow][skq + 4 * m] = ap;
            *(uint2*)&Bsb[srow][skq + 4 * m] = bp;
        }
        __syncthreads();
        if (c < 7) {      // prefetch next chunk
            const int kb = (c + 1) * 96;
            #pragma unroll
            for (int m = 0; m < 3; ++m) {
                pa[m] = *(const float4*)&arow[kb + 4 * m];
                pb[m] = *(const float4*)&brow[kb + 4 * m];
            }
        }
        #pragma unroll
        for (int kc = 0; kc < 96; kc += 32) {
            const short8 a0 = *(const short8*)&Asb[wm + fr][kc + fk];
            const short8 b0 = *(const short8*)&Bsb[wn + fr][kc + fk];
            acc = __builtin_amdgcn_mfma_f32_16x16x32_bf16(a0, b0, acc, 0, 0, 0);
        }
        __syncthreads();
    }

    // epilogue: C/D layout row=(lane>>4)*4+reg, col=lane&15
    float* G = ws + OFF_G + (unsigned)mat * 65536u;
    const int crow0 = (lane >> 4) * 4;
    const int ccol = lane & 15;
    float ts = 0.f;
    #pragma unroll
    for (int reg = 0; reg < 4; ++reg) {
        const int row = m0 + wm + crow0 + reg;
        const int col = n0 + wn + ccol;
        G[row * 256 + col] = acc[reg];
        ts += acc[reg];
    }
    if (m0 == n0 && wm == wn && (lane >> 4) == (ccol >> 2)) {
        // diagonal lanes: reg = ccol&3 hits row==col within diagonal quadrant
        ws[OFF_DIAG + (unsigned)(mat * 256 + m0 + wm + ccol)] = acc[ccol & 3];
    }
    const float tsum = block_reduce_sum(ts, redg);
    if (t == 0) ws[OFF_TSUM + (unsigned)(mat * 64 + tile)] = tsum;
}

// ---------------------------------------------------------------------------
// K2: mega kernel + inline finalize. 960 blocks x 256 threads, co-resident
// (LDS ~21KB, bounds(256,4) -> 4/CU -> capacity 1024 >= 960).
// blocks 0..575 angle (36 unordered 32x32 (i,k)-tile pairs x 16 j-tiles,
// weight 2 off-diag / 1 diag), 576..831 dist rows, 832..959 contrastive.
// Each block t0: slot sc1 store -> vmcnt(0) -> flag sc1 store; block 0 polls
// all 960 flags and finalizes into out.
// ---------------------------------------------------------------------------
__global__ __launch_bounds__(256, 4) void mega_kernel(float* __restrict__ ws,
                                                      float* __restrict__ out) {
    const float* Pg = ws + OFF_G;      // [2][65536]
    const float* Dg = ws + OFF_DIAG;   // [2][256]
    __shared__ float sGJ[16][36], sTJ[16][36], sIJ[16][36], sITJ[16][36];
    __shared__ float sGI[32][36], sTI[32][36];
    __shared__ float dgS[256], dgT[256];
    __shared__ float red1[4], red2[4], redS[1];
    const int b = blockIdx.x, t = threadIdx.x;

    if (b < NB_ANG) {
        // ---------------- angle (i<k symmetric tiling) ----------------
        const int pr = b >> 4;          // 0..35 unordered tile pair
        const int jt = b & 15;
        int ti = 0, rem = pr;
        while (rem >= 8 - ti) { rem -= 8 - ti; ++ti; }
        const int tk = ti + rem;        // ti <= tk
        const int i0 = ti * 32, k0 = tk * 32, j0 = jt * 16;
        const float wgt = (ti == tk) ? 1.f : 2.f;

        const int jj = t & 15, iw = t >> 4;
        const int i1 = i0 + iw, i2 = i1 + 16, j = j0 + jj;

        // diag (thread t owns index t)
        dgS[t] = Dg[t];
        dgT[t] = Dg[256 + t];

        // J-side G rows -> registers (1 float2 slot/thread: 16 rows x 32 k)
        const int r = t >> 4, c2 = (t & 15) * 2;
        const unsigned baseJ = (unsigned)((j0 + r) * 256 + k0 + c2);
        const float2 gjs = *(const float2*)&Pg[baseJ];
        const float2 gjt = *(const float2*)&Pg[65536u + baseJ];

        // I-side G rows -> LDS (1 float4 slot/thread: 32 rows x 32 k)
        const int ri = t >> 3, ci = (t & 7) * 4;
        const unsigned baseI = (unsigned)((i0 + ri) * 256 + k0 + ci);
        *(float4*)&sGI[ri][ci] = *(const float4*)&Pg[baseI];
        *(float4*)&sTI[ri][ci] = *(const float4*)&Pg[65536u + baseI];

        // per-thread G[i1,j], G[i2,j] (both mats)
        const float g1s = Pg[(unsigned)(i1 * 256 + j)];
        const float g1t = Pg[65536u + (unsigned)(i1 * 256 + j)];
        const float g2s = Pg[(unsigned)(i2 * 256 + j)];
        const float g2t = Pg[65536u + (unsigned)(i2 * 256 + j)];
        __syncthreads();   // dgS/dgT + I arrays ready

        // write J arrays + on-the-fly INV (float2 per thread)
        {
            const float djs = dgS[j0 + r], djt = dgT[j0 + r];
            const float dk0 = dgS[k0 + c2], dk1 = dgS[k0 + c2 + 1];
            const float ek0 = dgT[k0 + c2], ek1 = dgT[k0 + c2 + 1];
            float2 ivs, ivt;
            ivs.x = 1.f / (sqrtf(fmaxf(djs + dk0 - 2.f * gjs.x, 0.f)) + EPSF);
            ivs.y = 1.f / (sqrtf(fmaxf(djs + dk1 - 2.f * gjs.y, 0.f)) + EPSF);
            ivt.x = 1.f / (sqrtf(fmaxf(djt + ek0 - 2.f * gjt.x, 0.f)) + EPSF);
            ivt.y = 1.f / (sqrtf(fmaxf(djt + ek1 - 2.f * gjt.y, 0.f)) + EPSF);
            *(float2*)&sGJ[r][c2] = gjs;
            *(float2*)&sTJ[r][c2] = gjt;
            *(float2*)&sIJ[r][c2] = ivs;
            *(float2*)&sITJ[r][c2] = ivt;
        }
        // per-thread constants
        const float Gjj = dgS[j], Tjj = dgT[j];
        const float wis1 = 1.f / (sqrtf(fmaxf(dgS[i1] + Gjj - 2.f * g1s, 0.f)) + EPSF);
        const float wit1 = 1.f / (sqrtf(fmaxf(dgT[i1] + Tjj - 2.f * g1t, 0.f)) + EPSF);
        const float wis2 = 1.f / (sqrtf(fmaxf(dgS[i2] + Gjj - 2.f * g2s, 0.f)) + EPSF);
        const float wit2 = 1.f / (sqrtf(fmaxf(dgT[i2] + Tjj - 2.f * g2t, 0.f)) + EPSF);
        const float as1 = (Gjj - g1s) * wis1;
        const float at1 = (Tjj - g1t) * wit1;
        const float as2 = (Gjj - g2s) * wis2;
        const float at2 = (Tjj - g2t) * wit2;
        __syncthreads();   // J arrays ready

        float sum1 = 0.f, sum2 = 0.f;
        #pragma unroll
        for (int c = 0; c < 32; c += 4) {
            const float4 gJ  = *(const float4*)&sGJ[jj][c];
            const float4 iJ  = *(const float4*)&sIJ[jj][c];
            const float4 tJ  = *(const float4*)&sTJ[jj][c];
            const float4 itJ = *(const float4*)&sITJ[jj][c];
            const float4 a1 = *(const float4*)&sGI[iw][c];
            const float4 b1 = *(const float4*)&sTI[iw][c];
            const float4 a2 = *(const float4*)&sGI[iw + 16][c];
            const float4 b2 = *(const float4*)&sTI[iw + 16][c];
            const float gJr[4]  = {gJ.x, gJ.y, gJ.z, gJ.w};
            const float iJr[4]  = {iJ.x, iJ.y, iJ.z, iJ.w};
            const float tJr[4]  = {tJ.x, tJ.y, tJ.z, tJ.w};
            const float itJr[4] = {itJ.x, itJ.y, itJ.z, itJ.w};
            const float a1r[4] = {a1.x, a1.y, a1.z, a1.w};
            const float b1r[4] = {b1.x, b1.y, b1.z, b1.w};
            const float a2r[4] = {a2.x, a2.y, a2.z, a2.w};
            const float b2r[4] = {b2.x, b2.y, b2.z, b2.w};
            #pragma unroll
            for (int e = 0; e < 4; ++e) {
                const float ps1 = fmaf(wis1, a1r[e] - gJr[e], as1) * iJr[e];
                const float pt1 = fmaf(wit1, b1r[e] - tJr[e], at1) * itJr[e];
                const float d1 = ps1 - pt1;
                const float ad1 = fabsf(d1);
                const float m1 = fminf(ad1, 1.f);
                sum1 = fmaf(m1, fmaf(-0.5f, m1, ad1), sum1);

                const float ps2 = fmaf(wis2, a2r[e] - gJr[e], as2) * iJr[e];
                const float pt2 = fmaf(wit2, b2r[e] - tJr[e], at2) * itJr[e];
                const float d2 = ps2 - pt2;
                const float ad2 = fabsf(d2);
                const float m2 = fminf(ad2, 1.f);
                sum2 = fmaf(m2, fmaf(-0.5f, m2, ad2), sum2);
            }
        }
        const float v = block_reduce_sum(sum1 + sum2, red1);
        if (t == 0) {
            st_agent_f(ws + OFF_SLOT + SL_ANG + b, v * wgt);
            asm volatile("s_waitcnt vmcnt(0)" ::: "memory");
            st_agent_u((unsigned*)(ws + OFF_FLAG2) + b, MAGIC);
        }
    } else if (b < NB_ANG + 256) {
        // ---------------- distance row ----------------
        const int i = b - NB_ANG, j = t;
        const float gs  = Pg[(unsigned)(i * 256 + j)];
        const float gt  = Pg[65536u + (unsigned)(i * 256 + j)];
        const float djs = Dg[j], djt = Dg[256 + j];
        const float dis = Dg[i], dit = Dg[256 + i];
        const float ds = fmaxf(dis + djs - 2.f * gs, 0.f);
        const float dt = fmaxf(dit + djt - 2.f * gt, 0.f);

        // analytic masked pair-sums: sum_{i<j} d = N*tr - sum_all(G)
        const float tr_s = block_reduce_sum(djs, red1);
        const float tr_t = block_reduce_sum(djt, red1);
        const float tv = (t < 128) ? ws[OFF_TSUM + t] : 0.f;  // [2][64] linear
        const float sum_gs = block_reduce_sum((t < 64) ? tv : 0.f, red1);
        const float sum_gt = block_reduce_sum((t >= 64) ? tv : 0.f, red1);
        const float rs = 1.f / ((256.f * tr_s - sum_gs) / 32640.f + EPSF);
        const float rt = 1.f / ((256.f * tr_t - sum_gt) / 32640.f + EPSF);

        const float dd = ds * rs - dt * rt;
        const float a = fabsf(dd);
        const float m = fminf(a, 1.f);
        const float hv = block_reduce_sum((j > i) ? m * fmaf(-0.5f, m, a) : 0.f, red1);
        if (t == 0) {
            st_agent_f(ws + OFF_SLOT + SL_DIST + i, hv);
            asm volatile("s_waitcnt vmcnt(0)" ::: "memory");
            st_agent_u((unsigned*)(ws + OFF_FLAG2) + b, MAGIC);
        }
    } else {
        // ---------------- contrastive row ----------------
        const int rrow = b - (NB_ANG + 256), j = t;
        const float gs = (j >= 128) ? Pg[(unsigned)(rrow * 256 + j)] : 0.f;
        const float s = (j >= 128) ? 20.f * gs : -INFINITY;
        if (j == 128 + rrow) redS[0] = s;     // diag score
        float mx0 = wave_reduce_max(s);
        __syncthreads();
        if ((t & 63) == 0) red2[t >> 6] = mx0;
        __syncthreads();
        const float mx = fmaxf(fmaxf(red2[0], red2[1]), fmaxf(red2[2], red2[3]));
        const float e = block_reduce_sum((j >= 128) ? expf(s - mx) : 0.f, red1);
        if (t == 0) {
            st_agent_f(ws + OFF_SLOT + SL_CON + rrow, mx + logf(e) - redS[0]);
            asm volatile("s_waitcnt vmcnt(0)" ::: "memory");
            st_agent_u((unsigned*)(ws + OFF_FLAG2) + b, MAGIC);
        }
    }

    // ============== finalize (block 0 only) ==========
    if (b == 0) {
        for (int k = t; k < NB_ALL; k += 256) {   // one block polls: no storm
            while (ld_agent_u((const unsigned*)(ws + OFF_FLAG2) + k) != MAGIC)
                __builtin_amdgcn_s_sleep(4);
        }
        asm volatile("s_waitcnt vmcnt(0)" ::: "memory");
        __builtin_amdgcn_sched_barrier(0);
        __syncthreads();

        float* S = ws + OFF_SLOT;
        const float a_ = block_reduce_sum(
            ld_agent_f(S + SL_ANG + t) + ld_agent_f(S + SL_ANG + 256 + t) +
            ((t < 64) ? ld_agent_f(S + SL_ANG + 512 + t) : 0.f), red1);
        const float d_ = block_reduce_sum(ld_agent_f(S + SL_DIST + t), red1);
        const float c_ = block_reduce_sum((t < 128) ? ld_agent_f(S + SL_CON + t)
                                                    : 0.f, red1);
        if (t == 0) {
            const float contrastive = c_ / 128.f;
            const float dist = d_ / 32640.f;
            const float ang = a_ / 16581120.f;   // 256*255*254
            const float kd = 0.5f * (dist + ang);
            out[0] = contrastive + kd;
            out[1] = contrastive;
            out[2] = kd;
        }
    }
}

extern "C" void kernel_launch(void* const* d_in, const int* in_sizes, int n_in,
                              void* d_out, int out_size, void* d_ws, size_t ws_size,
                              hipStream_t stream) {
    (void)in_sizes; (void)n_in; (void)out_size; (void)ws_size;
    const float* sq = (const float*)d_in[0];
    const float* sp = (const float*)d_in[1];
    const float* tq = (const float*)d_in[2];
    const float* tp = (const float*)d_in[3];
    float* ws  = (float*)d_ws;
    float* out = (float*)d_out;

    gemm_kernel<<<128, 256, 0, stream>>>(sq, sp, tq, tp, ws);
    mega_kernel<<<NB_ALL, 256, 0, stream>>>(ws, out);
}